// Round 6
// baseline (367.555 us; speedup 1.0000x reference)
//
#include <hip/hip_runtime.h>
#include <math.h>

#pragma clang fp contract(off)

#define NLVL 5
#define TOTALN 261888
#define NBATCH 16
#define CAP 1024
#define NPROB (NBATCH * NLVL)
#define POST_N 1000
#define NMS_TH 0.7f
#define MINSZ 1e-3f
#define IMGSZ 1024.0f
#define BBOX_CLIP 4.135166556742356f

#define HBINS 2048
#define CCAP 4096
#define NCHUNK 256   // ceil(261888/1024); level offsets are all multiples of 1024

__constant__ int c_loff[NLVL] = {0, 196608, 245760, 258048, 261120};
__constant__ int c_num[NLVL]  = {196608, 49152, 12288, 3072, 768};
__constant__ int c_k[NLVL]    = {1000, 1000, 1000, 1000, 768};

// (rg, wg) tile list for the upper-triangular mask: wg >= rg
__constant__ int c_rg[10] = {0,0,0,0,1,1,1,2,2,3};
__constant__ int c_wg[10] = {0,1,2,3,1,2,3,2,3,3};

__device__ __forceinline__ unsigned monokey(float f) {
    unsigned b = __float_as_uint(f);
    return (b & 0x80000000u) ? ~b : (b | 0x80000000u);
}

__device__ __forceinline__ int lvl_of_start(int start) {
    return (start >= 261120) ? 4 : (start >= 258048) ? 3 : (start >= 245760) ? 2
         : (start >= 196608) ? 1 : 0;
}

// ---------------- pass 1: per-chunk LDS histogram of top-11 key bits ----------------
__global__ __launch_bounds__(256) void hist_kernel(const float* __restrict__ obj_all,
                                                   unsigned* __restrict__ ghist) {
    __shared__ unsigned lh[HBINS];
    const int tid = threadIdx.x;
    const int chunk = blockIdx.x;
    const int img = chunk >> 8, c = chunk & 255;
    const int start = c << 10;
    const int lvl = lvl_of_start(start);
    const int nrem = min(1024, TOTALN - start);
    for (int i = tid; i < HBINS; i += 256) lh[i] = 0;
    __syncthreads();
    const float* o = obj_all + (size_t)img * TOTALN + start;
    for (int i = tid; i < nrem; i += 256) atomicAdd(&lh[monokey(o[i]) >> 21], 1u);
    __syncthreads();
    unsigned* gh = ghist + (size_t)(img * NLVL + lvl) * HBINS;
    for (int i = tid; i < HBINS; i += 256) {
        unsigned v = lh[i];
        if (v) atomicAdd(&gh[i], v);
    }
}

// ---------------- pick threshold bucket b1 per problem (suffix-sum of hist) ----------------
__global__ __launch_bounds__(256) void pick1_kernel(const unsigned* __restrict__ ghist,
                                                    unsigned* __restrict__ b1out) {
    __shared__ unsigned suf[HBINS];
    const int p = blockIdx.x, tid = threadIdx.x;
    const int k = c_k[p % NLVL];
    const unsigned* gh = ghist + (size_t)p * HBINS;
    for (int i = tid; i < HBINS; i += 256) suf[i] = gh[i];
    __syncthreads();
    for (int d = 1; d < HBINS; d <<= 1) {
        unsigned v[HBINS / 256];
#pragma unroll
        for (int r = 0; r < HBINS / 256; ++r) {
            int i = tid + r * 256;
            v[r] = suf[i] + ((i + d < HBINS) ? suf[i + d] : 0u);
        }
        __syncthreads();
#pragma unroll
        for (int r = 0; r < HBINS / 256; ++r) suf[tid + r * 256] = v[r];
        __syncthreads();
    }
#pragma unroll
    for (int r = 0; r < HBINS / 256; ++r) {
        int i = tid + r * 256;
        if (suf[i] >= (unsigned)k && (i == HBINS - 1 || suf[i + 1] < (unsigned)k))
            b1out[p] = (unsigned)i;
    }
}

// ---------------- pass 2: compact all keys >= (b1<<21) ----------------
__global__ __launch_bounds__(256) void compact_kernel(const float* __restrict__ obj_all,
                                                      const unsigned* __restrict__ b1in,
                                                      int* __restrict__ cnt,
                                                      unsigned long long* __restrict__ cand) {
    __shared__ unsigned long long lkey[1024];
    __shared__ int s_lc, s_base;
    const int tid = threadIdx.x;
    const int chunk = blockIdx.x;
    const int img = chunk >> 8, c = chunk & 255;
    const int start = c << 10;
    const int lvl = lvl_of_start(start);
    const int nrem = min(1024, TOTALN - start);
    const int p = img * NLVL + lvl;
    const unsigned thr = b1in[p] << 21;
    const int local0 = start - c_loff[lvl];
    if (tid == 0) s_lc = 0;
    __syncthreads();
    const float* o = obj_all + (size_t)img * TOTALN + start;
    for (int i = tid; i < nrem; i += 256) {
        unsigned key = monokey(o[i]);
        if (key >= thr) {
            int l = atomicAdd(&s_lc, 1);
            lkey[l] = (((unsigned long long)key) << 32) | (unsigned)(~(unsigned)(local0 + i));
        }
    }
    __syncthreads();
    if (tid == 0) s_base = atomicAdd(&cnt[p], s_lc);
    __syncthreads();
    const int lc = s_lc, base = s_base;
    unsigned long long* cd = cand + (size_t)p * CCAP;
    for (int i = tid; i < lc; i += 256) {
        int pos = base + i;
        if (pos < CCAP) cd[pos] = lkey[i];
    }
}

// ---------------- finalize via rank: pos_i = #{j : key_j > key_i}, barrier-free ----------------
__global__ __launch_bounds__(256) void rank_kernel(const unsigned long long* __restrict__ cand,
                                                   const int* __restrict__ cnt,
                                                   unsigned* __restrict__ sel) {
    __shared__ unsigned long long skey[CCAP];
    const int p = blockIdx.x >> 4;
    const int blk = blockIdx.x & 15;
    const int tid = threadIdx.x;
    const int lvl = p % NLVL, k = c_k[lvl];
    int n = cnt[p]; if (n > CCAP) n = CCAP;
    const int i0 = blk << 8;
    if (i0 >= n) return;                       // block-uniform exit, no barrier crossed
    const unsigned long long* cd = cand + (size_t)p * CCAP;
    const int n8 = (n + 7) & ~7;
    for (int i = tid; i < n8; i += 256) skey[i] = (i < n) ? cd[i] : 0ull;
    __syncthreads();
    const int i = i0 + tid;
    const unsigned long long my = (i < n) ? skey[i] : ~0ull;  // sentinel -> rank 0, not emitted
    int rank = 0;
    for (int j = 0; j < n8; j += 8) {          // wave-uniform LDS broadcast reads
        unsigned long long k0 = skey[j + 0], k1 = skey[j + 1];
        unsigned long long k2 = skey[j + 2], k3 = skey[j + 3];
        unsigned long long k4 = skey[j + 4], k5 = skey[j + 5];
        unsigned long long k6 = skey[j + 6], k7 = skey[j + 7];
        rank += (int)(k0 > my) + (int)(k1 > my) + (int)(k2 > my) + (int)(k3 > my)
              + (int)(k4 > my) + (int)(k5 > my) + (int)(k6 > my) + (int)(k7 > my);
    }
    if (i < n && rank < k) {
        unsigned li = ~(unsigned)(my & 0xFFFFFFFFull);
        sel[p * CAP + rank] = (unsigned)c_loff[lvl] + li;
    }
}

// ---------------- decode + clip + validity + sigmoid ----------------
__global__ __launch_bounds__(256) void decode_kernel(
    const float* __restrict__ obj_all, const float* __restrict__ deltas,
    const float* __restrict__ anchors, const unsigned* __restrict__ sel,
    float* __restrict__ cx1, float* __restrict__ cy1,
    float* __restrict__ cx2, float* __restrict__ cy2, float* __restrict__ csc) {
    int g = blockIdx.x * 256 + threadIdx.x;
    if (g >= NPROB * CAP) return;
    int p = g >> 10, r = g & (CAP - 1);
    int img = p / NLVL, lvl = p % NLVL;
    int k = c_k[lvl];
    float x1 = 0.f, y1 = 0.f, x2 = 0.f, y2 = 0.f, scv = -1.0f;
    if (r < k) {
        unsigned idx = sel[p * CAP + r];
        if (idx < (unsigned)TOTALN) {
            float o = obj_all[(size_t)img * TOTALN + idx];
            const float* dd = deltas + ((size_t)img * TOTALN + (size_t)idx) * 4;
            const float* aa = anchors + (size_t)idx * 4;
            float a0 = aa[0], a1 = aa[1], a2 = aa[2], a3 = aa[3];
            float w = a2 - a0, h = a3 - a1;
            float cx = a0 + 0.5f * w, cy = a1 + 0.5f * h;
            float dx = dd[0], dy = dd[1];
            float dw = fminf(dd[2], BBOX_CLIP), dh = fminf(dd[3], BBOX_CLIP);
            float pcx = dx * w + cx, pcy = dy * h + cy;
            float pw = expf(dw) * w, ph = expf(dh) * h;
            float bx1 = pcx - 0.5f * pw, by1 = pcy - 0.5f * ph;
            float bx2 = pcx + 0.5f * pw, by2 = pcy + 0.5f * ph;
            x1 = fminf(fmaxf(bx1, 0.f), IMGSZ);
            y1 = fminf(fmaxf(by1, 0.f), IMGSZ);
            x2 = fminf(fmaxf(bx2, 0.f), IMGSZ);
            y2 = fminf(fmaxf(by2, 0.f), IMGSZ);
            float wsz = x2 - x1, hsz = y2 - y1;
            if (wsz >= MINSZ && hsz >= MINSZ) scv = 1.0f / (1.0f + expf(-o));
        }
    }
    cx1[g] = x1; cy1[g] = y1; cx2[g] = x2; cy2[g] = y2; csc[g] = scv;
}

// ---------------- NMS phase 1: pairwise suppression-bit matrix (tiled) ----------------
__global__ __launch_bounds__(256) void mask_kernel(
    const float* __restrict__ cx1, const float* __restrict__ cy1,
    const float* __restrict__ cx2, const float* __restrict__ cy2,
    unsigned long long* __restrict__ mask) {
    __shared__ float sx1[256], sy1[256], sx2[256], sy2[256], sar[256];
    const int bid = blockIdx.x;
    const int p = bid / 10, pair = bid - p * 10;
    const int rg = c_rg[pair], wg = c_wg[pair];
    const int tid = threadIdx.x;
    const int base = p * CAP;

    {   // stage the 256 column boxes of this word-group
        const int j = base + (wg << 8) + tid;
        float a = cx1[j], b = cy1[j], c = cx2[j], d = cy2[j];
        sx1[tid] = a; sy1[tid] = b; sx2[tid] = c; sy2[tid] = d;
        sar[tid] = (c - a) * (d - b);
    }
    const int i = (rg << 8) + tid;
    const float ix1 = cx1[base + i], iy1 = cy1[base + i];
    const float ix2 = cx2[base + i], iy2 = cy2[base + i];
    const float iar = (ix2 - ix1) * (iy2 - iy1);
    __syncthreads();

    unsigned long long* mr = mask + ((size_t)(base + i) << 4);
    const int w0 = i >> 6;                    // wave-uniform (64 consecutive rows/wave)
#pragma unroll
    for (int ww = 0; ww < 4; ++ww) {
        const int w = (wg << 2) + ww;
        if (w < w0) continue;                 // wave-uniform skip
        unsigned long long bits = 0;
        const int jl0 = ww << 6;
        const int jg0 = w << 6;
#pragma unroll 8
        for (int jj = 0; jj < 64; ++jj) {
            const int jl = jl0 + jj;
            float ltx = fmaxf(ix1, sx1[jl]), lty = fmaxf(iy1, sy1[jl]);
            float rbx = fminf(ix2, sx2[jl]), rby = fminf(iy2, sy2[jl]);
            float wx = fmaxf(rbx - ltx, 0.f), wy = fmaxf(rby - lty, 0.f);
            float inter = wx * wy;
            float iou = inter / ((iar + sar[jl]) - inter);
            if (iou > NMS_TH && (jg0 + jj) > i) bits |= (1ull << jj);
        }
        mr[w] = bits;
    }
}

// ---------------- NMS phase 2: sparse bit-scan (uniform ffs chain, lazy mask reads) ----
// Wave 0 scans; waves 1-3 wait and then parallelize the survivor writeback.
// rem: lane l owns removal word (l&15) for future groups (4-way replicated).
// s_cur: current group's removal word, uniform in all lanes. Per accepted row,
// intra-group suppression comes from a preloaded per-lane diagonal register via
// one shuffle; cross-group words are read lazily (only accepted rows) in a
// 32-slot batched load at group end.
__global__ __launch_bounds__(256) void scan_kernel(
    const unsigned long long* __restrict__ mask,
    const float* __restrict__ cx1, const float* __restrict__ cy1,
    const float* __restrict__ cx2, const float* __restrict__ cy2,
    const float* __restrict__ csc,
    float* __restrict__ svbox, float* __restrict__ svsc, int* __restrict__ svcnt) {
    __shared__ unsigned short survL[CAP];
    __shared__ int s_ns;
    const int p = blockIdx.x, tid = threadIdx.x;
    const int base = p * CAP;

    if (tid < 64) {
        const int lane = tid;
        const int wsel = lane & 15;
        const unsigned long long* gm = mask + ((size_t)base << 4);

        // init rem from scores: 16 coalesced loads + ballots
        unsigned long long rem = 0;
#pragma unroll
        for (int c = 0; c < 16; ++c) {
            float s = csc[base + (c << 6) + lane];
            unsigned long long w = __ballot(s <= 0.f);
            if (wsel == c) rem = w;
        }

        // prefetch diag of group 0: lane j holds mask[row j][word 0]
        unsigned long long dg = gm[(size_t)lane * 16 + 0];
        int ns = 0;

        for (int g = 0; g < 16; ++g) {
            unsigned long long dgn = 0;   // prefetch next group's diagonal
            if (g < 15)
                dgn = gm[(size_t)(((g + 1) << 6) + lane) * 16 + (g + 1)];

            unsigned long long s_cur = __shfl(rem, g);   // lane g owns word g
            unsigned long long alive = ~s_cur;
            unsigned long long acc = 0;
            while (alive) {
                int b = __ffsll((long long)alive) - 1;
                unsigned long long d = __shfl(dg, b);
                alive &= ~(d | (1ull << b));
                acc |= (1ull << b);
            }

            // survivors (ascending) + batched lazy rem update, 32 rows in flight
            unsigned long long t = acc;
            while (t) {
                int rb[32];
#pragma unroll
                for (int q = 0; q < 32; ++q) {
                    rb[q] = t ? (__ffsll((long long)t) - 1) : -1;
                    t &= t - 1;
                }
#pragma unroll
                for (int q = 0; q < 32; ++q) {
                    if (rb[q] >= 0) { survL[ns] = (unsigned short)((g << 6) + rb[q]); ++ns; }
                }
                unsigned long long vv[32];
#pragma unroll
                for (int q = 0; q < 32; ++q) {
                    // always-valid address; dummy slots masked to 0 after load
                    const int row = (g << 6) + (rb[q] >= 0 ? rb[q] : 0);
                    vv[q] = gm[(size_t)row * 16 + wsel];
                }
                unsigned long long o = 0;
#pragma unroll
                for (int q = 0; q < 32; ++q)
                    o |= (rb[q] >= 0) ? vv[q] : 0ull;
                rem |= o;
            }
            dg = dgn;
        }
        if (lane == 0) s_ns = ns;
    }
    __syncthreads();
    const int ns = s_ns;
    for (int s = tid; s < ns; s += 256) {
        int r = survL[s];
        int o = base + s;
        svsc[o] = csc[base + r];
        svbox[(size_t)o * 4 + 0] = cx1[base + r];
        svbox[(size_t)o * 4 + 1] = cy1[base + r];
        svbox[(size_t)o * 4 + 2] = cx2[base + r];
        svbox[(size_t)o * 4 + 3] = cy2[base + r];
    }
    if (tid == 0) svcnt[p] = ns;
}

// ---------------- merge 5 survivor lists per image by score (ties -> lower level) ----------------
__global__ __launch_bounds__(256) void merge_kernel(
    const float* __restrict__ svbox, const float* __restrict__ svsc,
    const int* __restrict__ svcnt, float* __restrict__ out) {
    __shared__ float sls[NLVL][CAP];
    __shared__ int scnt[NLVL];
    const int img = blockIdx.x, tid = threadIdx.x;
    if (tid < NLVL) scnt[tid] = svcnt[img * NLVL + tid];
    __syncthreads();
    for (int l = 0; l < NLVL; ++l) {
        int c = scnt[l];
        for (int i = tid; i < c; i += 256) sls[l][i] = svsc[(img * NLVL + l) * CAP + i];
    }
    __syncthreads();
    for (int l = 0; l < NLVL; ++l) {
        int c = scnt[l];
        for (int i = tid; i < c; i += 256) {
            float s = sls[l][i];
            int pos = i;
            for (int m = 0; m < NLVL; ++m) {
                if (m == l) continue;
                int n2 = scnt[m];
                int lo = 0, hi = n2;
                if (m < l) {
                    while (lo < hi) { int mid = (lo + hi) >> 1; if (sls[m][mid] >= s) lo = mid + 1; else hi = mid; }
                } else {
                    while (lo < hi) { int mid = (lo + hi) >> 1; if (sls[m][mid] > s)  lo = mid + 1; else hi = mid; }
                }
                pos += lo;
            }
            if (pos < POST_N) {
                int src = (img * NLVL + l) * CAP + i;
                float* o = out + ((size_t)img * POST_N + pos) * 5;
                o[0] = svbox[(size_t)src * 4 + 0];
                o[1] = svbox[(size_t)src * 4 + 1];
                o[2] = svbox[(size_t)src * 4 + 2];
                o[3] = svbox[(size_t)src * 4 + 3];
                o[4] = s;
            }
        }
    }
}

extern "C" void kernel_launch(void* const* d_in, const int* in_sizes, int n_in,
                              void* d_out, int out_size, void* d_ws, size_t ws_size,
                              hipStream_t stream) {
    const float* obj     = (const float*)d_in[0];
    const float* deltas  = (const float*)d_in[1];
    const float* anchors = (const float*)d_in[2];
    float* out = (float*)d_out;

    char* w = (char*)d_ws;
    size_t off = 0;
    auto alloc = [&](size_t bytes) -> void* {
        void* pp = w + off;
        off += (bytes + 511) & ~(size_t)511;
        return pp;
    };
    unsigned* ghist = (unsigned*)alloc((size_t)NPROB * HBINS * 4);
    unsigned* b1buf = (unsigned*)alloc((size_t)NPROB * 4);
    int*      ccnt  = (int*)alloc((size_t)NPROB * 4);
    unsigned long long* cand = (unsigned long long*)alloc((size_t)NPROB * CCAP * 8);
    unsigned* sel = (unsigned*)alloc((size_t)NPROB * CAP * 4);
    float* cx1 = (float*)alloc((size_t)NPROB * CAP * 4);
    float* cy1 = (float*)alloc((size_t)NPROB * CAP * 4);
    float* cx2 = (float*)alloc((size_t)NPROB * CAP * 4);
    float* cy2 = (float*)alloc((size_t)NPROB * CAP * 4);
    float* csc = (float*)alloc((size_t)NPROB * CAP * 4);
    float* svbox = (float*)alloc((size_t)NPROB * CAP * 16);
    float* svsc  = (float*)alloc((size_t)NPROB * CAP * 4);
    int*   svcnt = (int*)alloc((size_t)NPROB * 4);
    unsigned long long* nmask = (unsigned long long*)alloc((size_t)NPROB * CAP * 16 * 8);
    if (off > ws_size) return;  // fail cleanly (output stays poisoned -> visible failure)

    hipMemsetAsync(ghist, 0, (size_t)NPROB * HBINS * 4, stream);
    hipMemsetAsync(ccnt, 0, (size_t)NPROB * 4, stream);
    hipMemsetAsync(d_out, 0, (size_t)out_size * sizeof(float), stream);

    hist_kernel<<<NBATCH * NCHUNK, 256, 0, stream>>>(obj, ghist);
    pick1_kernel<<<NPROB, 256, 0, stream>>>(ghist, b1buf);
    compact_kernel<<<NBATCH * NCHUNK, 256, 0, stream>>>(obj, b1buf, ccnt, cand);
    rank_kernel<<<NPROB * 16, 256, 0, stream>>>(cand, ccnt, sel);
    decode_kernel<<<(NPROB * CAP) / 256, 256, 0, stream>>>(obj, deltas, anchors, sel,
                                                           cx1, cy1, cx2, cy2, csc);
    mask_kernel<<<NPROB * 10, 256, 0, stream>>>(cx1, cy1, cx2, cy2, nmask);
    scan_kernel<<<NPROB, 256, 0, stream>>>(nmask, cx1, cy1, cx2, cy2, csc, svbox, svsc, svcnt);
    merge_kernel<<<NBATCH, 256, 0, stream>>>(svbox, svsc, svcnt, out);
}